// Round 4
// baseline (100.188 us; speedup 1.0000x reference)
//
#include <hip/hip_runtime.h>
#include <math.h>

#define SR      44100.0
#define T_LEN   441000
#define B_ROWS  32
#define CHUNK   32
#define NCH     13782           // ceil(441000/32); last chunk = 8 samples
#define WPR     216             // waves per row = ceil(NCH/64)
#define NWAVE   (B_ROWS * WPR)  // 6912
#define NBLK    (NWAVE / 4)     // 1728 blocks of 4 waves
#define SPAN    14              // chunks per kB thread: 1024*14 = 14336 >= 13782
#define ROUNDS  10

// ws layout (floats): only chunk states now
#define WS_F    0               // NCH*B_ROWS*6: finals -> entries (in place)

typedef __attribute__((address_space(1))) const void gconst_t;
typedef __attribute__((address_space(3))) void lds_t;
#define GL2LDS(gp, lp) __builtin_amdgcn_global_load_lds((gconst_t*)(gp), (lds_t*)(lp), 16, 0, 0)

// ---------------- shared helpers ----------------

// Per-block inline coefficient computation (deterministic across blocks).
// Call AFTER issuing staging loads; transcendental latency hides under them.
#define COMPUTE_COEFS_TO_LDS(scoef, qs, gains) do { \
    if (threadIdx.x < 3) { \
      int f = threadIdx.x; \
      double cfq = 100.0 * exp(log(30.0) * (double)f / 3.0); \
      double w0 = 2.0 * M_PI * cfq / SR; \
      double alpha = sin(w0) / (2.0 * (double)qs[f]); \
      double Ag = exp((double)gains[f] * (2.302585092994045684 / 40.0)); \
      double a0 = 1.0 + alpha / Ag; \
      scoef[f*5+0] = (float)((1.0 + alpha * Ag) / a0); \
      scoef[f*5+1] = (float)((-2.0 * cos(w0)) / a0); \
      scoef[f*5+2] = (float)((1.0 - alpha * Ag) / a0); \
      scoef[f*5+3] = (float)((-2.0 * cos(w0)) / a0); \
      scoef[f*5+4] = (float)((1.0 - alpha / Ag) / a0); \
    } \
  } while (0)

#define LOAD_COEFS(cf) \
  const float b00=cf[0],b10=cf[1],b20=cf[2],a10=cf[3],a20=cf[4]; \
  const float b01=cf[5],b11=cf[6],b21=cf[7],a11=cf[8],a21=cf[9]; \
  const float b02=cf[10],b12=cf[11],b22=cf[12],a12=cf[13],a22=cf[14];

#define CASCADE_STEP(xx) do { \
    float y1 = fmaf(b00, (xx), s11); \
    s11 = fmaf(-a10, y1, fmaf(b10, (xx), s21)); \
    s21 = fmaf(-a20, y1, b20 * (xx)); \
    float y2 = fmaf(b01, y1, s12); \
    s12 = fmaf(-a11, y2, fmaf(b11, y1, s22)); \
    s22 = fmaf(-a21, y2, b21 * y1); \
    y3 = fmaf(b02, y2, s13); \
    s13 = fmaf(-a12, y3, fmaf(b12, y2, s23)); \
    s23 = fmaf(-a22, y3, b22 * y2); \
  } while (0)

// Per-wave slab: 64 chunks x 32 floats, linear (no pad).
// Swizzle: LDS float4-slot s holds global float4 g(s) = (s&~7)|((s&7)^((s>>3)&7)).
// Involution; keeps coalescing within each 128B line; ds_read_b128 bank-balanced.

// ---------------- kA: chunk final states (zero entry) ----------------

__global__ __launch_bounds__(256) void kA_states(const float* __restrict__ x,
                                                 const float* __restrict__ qs,
                                                 const float* __restrict__ gains,
                                                 float* __restrict__ ws) {
  __shared__ float lds[4 * 2048];   // 4 waves x 8KB
  __shared__ float scoef[16];
  int wib = threadIdx.x >> 6, lane = threadIdx.x & 63;
  int gw = blockIdx.x * 4 + wib;
  int row = gw / WPR, wci = gw % WPR;
  long rowbase = (long)row * T_LEN;
  int s0 = wci << 11;                                // sample offset
  int span4 = (min(2048, T_LEN - s0)) >> 2;          // float4 count (512 or 170)
  const float4* xp = (const float4*)(x + rowbase + s0);
  float* slab = lds + (wib << 11);
  if (span4 == 512) {
    #pragma unroll
    for (int i = 0; i < 8; i++) {
      int s = (i << 6) + lane;
      int g = (s & ~7) | ((s & 7) ^ ((s >> 3) & 7));
      GL2LDS(xp + g, slab + (i << 8));
    }
  } else {
    #pragma unroll
    for (int i = 0; i < 8; i++) {
      int s = (i << 6) + lane;
      int g = (s & ~7) | ((s & 7) ^ ((s >> 3) & 7));
      if (g < span4) GL2LDS(xp + g, slab + (i << 8));
    }
  }
  COMPUTE_COEFS_TO_LDS(scoef, qs, gains);
  __syncthreads();
  int ci = (wci << 6) + lane;
  if (ci < NCH) {
    LOAD_COEFS(scoef);
    int rem = min(CHUNK, T_LEN - (ci << 5));
    int n4 = rem >> 2;                               // 8, or 2 for last chunk
    const float* rowp = slab + (lane << 5);
    int xr = lane & 7;
    float s11=0,s21=0,s12=0,s22=0,s13=0,s23=0, y3;
    if (n4 == 8) {
      #pragma unroll
      for (int j4 = 0; j4 < 8; j4++) {
        float4 v = *(const float4*)(rowp + ((j4 ^ xr) << 2));
        CASCADE_STEP(v.x); CASCADE_STEP(v.y); CASCADE_STEP(v.z); CASCADE_STEP(v.w);
      }
    } else {
      for (int j4 = 0; j4 < n4; j4++) {
        float4 v = *(const float4*)(rowp + ((j4 ^ xr) << 2));
        CASCADE_STEP(v.x); CASCADE_STEP(v.y); CASCADE_STEP(v.z); CASCADE_STEP(v.w);
      }
    }
    (void)y3;
    float* F = ws + WS_F + ((long)row * NCH + ci) * 6;
    F[0]=s11; F[1]=s21; F[2]=s12; F[3]=s22; F[4]=s13; F[5]=s23;
  }
}

// ---------------- kB: full per-row affine scan (one block per row) ----------------

__device__ __forceinline__ void mm6d(const double* X, const double* Y, double* Z, int t) {
  if (t < 36) {
    int i = t / 6, j = t % 6;
    double s = 0.0;
    #pragma unroll
    for (int k = 0; k < 6; k++) s += X[i*6+k] * Y[k*6+j];
    Z[t] = s;
  }
}

__global__ __launch_bounds__(1024) void kB_scan(const float* __restrict__ qs,
                                                const float* __restrict__ gains,
                                                float* __restrict__ ws) {
  int row = blockIdx.x, t = threadIdx.x;
  __shared__ double Da[36], Db[36], Dc[36], Dd[36];
  __shared__ float sW[36], sV[ROUNDS][36];
  __shared__ float bufA[1024][7], bufB[1024][7];

  if (t == 0) {
    // coefficients (double) + one-sample 6x6 cascade matrix A -> Da
    double dco[3][5];
    for (int f = 0; f < 3; f++) {
      double cfq = 100.0 * exp(log(30.0) * (double)f / 3.0);
      double w0 = 2.0 * M_PI * cfq / SR;
      double alpha = sin(w0) / (2.0 * (double)qs[f]);
      double Ag = exp((double)gains[f] * (2.302585092994045684 / 40.0));
      double a0 = 1.0 + alpha / Ag;
      dco[f][0] = (1.0 + alpha * Ag) / a0;
      dco[f][1] = (-2.0 * cos(w0)) / a0;
      dco[f][2] = (1.0 - alpha * Ag) / a0;
      dco[f][3] = (-2.0 * cos(w0)) / a0;
      dco[f][4] = (1.0 - alpha / Ag) / a0;
    }
    double u[7] = {0,0,0,0,0,0,1};  // current filter input as linear form over (S, x)
    for (int f = 0; f < 3; f++) {
      double b0=dco[f][0], b1=dco[f][1], b2=dco[f][2], a1=dco[f][3], a2=dco[f][4];
      double yv[7], s1p[7], s2p[7];
      for (int i = 0; i < 7; i++) {
        yv[i]  = b0 * u[i] + ((i == 2*f)   ? 1.0 : 0.0);
        s1p[i] = b1 * u[i] + ((i == 2*f+1) ? 1.0 : 0.0) - a1 * yv[i];
        s2p[i] = b2 * u[i] - a2 * yv[i];
      }
      for (int i = 0; i < 6; i++) { Da[(2*f)*6+i] = s1p[i]; Da[(2*f+1)*6+i] = s2p[i]; }
      for (int i = 0; i < 7; i++) u[i] = yv[i];
    }
  }
  __syncthreads();
  // W = A^32 via 5 squarings
  mm6d(Da, Da, Db, t); __syncthreads();   // A^2
  mm6d(Db, Db, Da, t); __syncthreads();   // A^4
  mm6d(Da, Da, Db, t); __syncthreads();   // A^8
  mm6d(Db, Db, Da, t); __syncthreads();   // A^16
  mm6d(Da, Da, Db, t); __syncthreads();   // A^32 = W  (Db)
  if (t < 36) sW[t] = (float)Db[t];
  // V0 = W^SPAN = W^14 = ((W * W^2) * W^4)^2
  mm6d(Db, Db, Da, t); __syncthreads();   // W^2  (Da)
  mm6d(Db, Da, Dc, t); __syncthreads();   // W^3  (Dc)
  mm6d(Da, Da, Dd, t); __syncthreads();   // W^4  (Dd)
  mm6d(Dc, Dd, Da, t); __syncthreads();   // W^7  (Da)
  mm6d(Da, Da, Dc, t); __syncthreads();   // W^14 (Dc) = V0
  if (t < 36) sV[0][t] = (float)Dc[t];
  {
    double* cur = Dc; double* oth = Dd;
    for (int k = 1; k < ROUNDS; k++) {
      mm6d(cur, cur, oth, t); __syncthreads();
      if (t < 36) sV[k][t] = (float)oth[t];
      double* tm = cur; cur = oth; oth = tm;
    }
  }
  __syncthreads();

  float* F = ws + WS_F + (long)row * NCH * 6;
  int j0 = t * SPAN, j1 = min(j0 + SPAN, NCH);
  // Phase A: fold own span from zero state
  float v[6] = {0,0,0,0,0,0};
  for (int j = j0; j < j1; j++) {
    const float* Fj = F + (long)j * 6;
    float nv[6];
    #pragma unroll
    for (int i = 0; i < 6; i++) {
      float s = Fj[i];
      #pragma unroll
      for (int k = 0; k < 6; k++) s = fmaf(sW[i*6+k], v[k], s);
      nv[i] = s;
    }
    #pragma unroll
    for (int i = 0; i < 6; i++) v[i] = nv[i];
  }
  #pragma unroll
  for (int i = 0; i < 6; i++) bufA[t][i] = v[i];
  __syncthreads();
  // Phase B: Hillis-Steele (tail threads' wrong inclusives are never consumed)
  float (*src)[7] = bufA, (*dst)[7] = bufB;
  for (int k = 0; k < ROUNDS; k++) {
    int d = 1 << k;
    float nv[6];
    if (t >= d) {
      #pragma unroll
      for (int i = 0; i < 6; i++) {
        float s = src[t][i];
        #pragma unroll
        for (int kk = 0; kk < 6; kk++) s = fmaf(sV[k][i*6+kk], src[t-d][kk], s);
        nv[i] = s;
      }
    } else {
      #pragma unroll
      for (int i = 0; i < 6; i++) nv[i] = src[t][i];
    }
    #pragma unroll
    for (int i = 0; i < 6; i++) dst[t][i] = nv[i];
    __syncthreads();
    float (*tm)[7] = src; src = dst; dst = tm;
  }
  float e[6];
  if (t > 0) { for (int i = 0; i < 6; i++) e[i] = src[t-1][i]; }
  else       { for (int i = 0; i < 6; i++) e[i] = 0.0f; }
  // Phase C: overwrite F[j] with entry state of chunk j
  for (int j = j0; j < j1; j++) {
    float* Fj = F + (long)j * 6;
    float nv[6];
    #pragma unroll
    for (int i = 0; i < 6; i++) {
      float s = Fj[i];
      #pragma unroll
      for (int k = 0; k < 6; k++) s = fmaf(sW[i*6+k], e[k], s);
      nv[i] = s;
    }
    #pragma unroll
    for (int i = 0; i < 6; i++) { Fj[i] = e[i]; e[i] = nv[i]; }
  }
}

// ---------------- kC: exact emit from entry states ----------------

__global__ __launch_bounds__(256) void kC_emit(const float* __restrict__ x,
                                               const float* __restrict__ qs,
                                               const float* __restrict__ gains,
                                               float* __restrict__ y,
                                               const float* __restrict__ ws) {
  __shared__ float lds[4 * 2048];
  __shared__ float scoef[16];
  int wib = threadIdx.x >> 6, lane = threadIdx.x & 63;
  int gw = blockIdx.x * 4 + wib;
  int row = gw / WPR, wci = gw % WPR;
  long rowbase = (long)row * T_LEN;
  int s0 = wci << 11;
  int span4 = (min(2048, T_LEN - s0)) >> 2;
  const float4* xp = (const float4*)(x + rowbase + s0);
  float* slab = lds + (wib << 11);
  if (span4 == 512) {
    #pragma unroll
    for (int i = 0; i < 8; i++) {
      int s = (i << 6) + lane;
      int g = (s & ~7) | ((s & 7) ^ ((s >> 3) & 7));
      GL2LDS(xp + g, slab + (i << 8));
    }
  } else {
    #pragma unroll
    for (int i = 0; i < 8; i++) {
      int s = (i << 6) + lane;
      int g = (s & ~7) | ((s & 7) ^ ((s >> 3) & 7));
      if (g < span4) GL2LDS(xp + g, slab + (i << 8));
    }
  }
  COMPUTE_COEFS_TO_LDS(scoef, qs, gains);
  int ci = (wci << 6) + lane;
  float e0=0,e1=0,e2=0,e3=0,e4=0,e5=0;
  if (ci < NCH) {
    const float* E = ws + WS_F + ((long)row * NCH + ci) * 6;
    e0=E[0]; e1=E[1]; e2=E[2]; e3=E[3]; e4=E[4]; e5=E[5];
  }
  __syncthreads();
  if (ci < NCH) {
    LOAD_COEFS(scoef);
    float s11=e0, s21=e1, s12=e2, s22=e3, s13=e4, s23=e5;
    int rem = min(CHUNK, T_LEN - (ci << 5));
    int n4 = rem >> 2;
    float* rowp = slab + (lane << 5);
    int xr = lane & 7;
    float y3;
    if (n4 == 8) {
      #pragma unroll
      for (int j4 = 0; j4 < 8; j4++) {
        float* p = rowp + ((j4 ^ xr) << 2);
        float4 v = *(const float4*)p;
        float4 o;
        CASCADE_STEP(v.x); o.x = y3;
        CASCADE_STEP(v.y); o.y = y3;
        CASCADE_STEP(v.z); o.z = y3;
        CASCADE_STEP(v.w); o.w = y3;
        *(float4*)p = o;
      }
    } else {
      for (int j4 = 0; j4 < n4; j4++) {
        float* p = rowp + ((j4 ^ xr) << 2);
        float4 v = *(const float4*)p;
        float4 o;
        CASCADE_STEP(v.x); o.x = y3;
        CASCADE_STEP(v.y); o.y = y3;
        CASCADE_STEP(v.z); o.z = y3;
        CASCADE_STEP(v.w); o.w = y3;
        *(float4*)p = o;
      }
    }
  }
  __syncthreads();
  float4* yp = (float4*)(y + rowbase + s0);
  if (span4 == 512) {
    #pragma unroll
    for (int i = 0; i < 8; i++) {
      int g = (i << 6) + lane;
      int s = (g & ~7) | ((g & 7) ^ ((g >> 3) & 7));
      yp[g] = *(const float4*)(slab + (s << 2));
    }
  } else {
    #pragma unroll
    for (int i = 0; i < 8; i++) {
      int g = (i << 6) + lane;
      int s = (g & ~7) | ((g & 7) ^ ((g >> 3) & 7));
      if (g < span4) yp[g] = *(const float4*)(slab + (s << 2));
    }
  }
}

extern "C" void kernel_launch(void* const* d_in, const int* in_sizes, int n_in,
                              void* d_out, int out_size, void* d_ws, size_t ws_size,
                              hipStream_t stream) {
  const float* audio = (const float*)d_in[0];
  const float* qs    = (const float*)d_in[1];
  const float* gains = (const float*)d_in[2];
  float* out = (float*)d_out;
  float* ws  = (float*)d_ws;

  hipLaunchKernelGGL(kA_states, dim3(NBLK), dim3(256), 0, stream, audio, qs, gains, ws);
  hipLaunchKernelGGL(kB_scan, dim3(B_ROWS), dim3(1024), 0, stream, qs, gains, ws);
  hipLaunchKernelGGL(kC_emit, dim3(NBLK), dim3(256), 0, stream, audio, qs, gains, out, ws);
}

// Round 5
// 68.576 us; speedup vs baseline: 1.4610x; 1.4610x over previous
//
#include <hip/hip_runtime.h>
#include <math.h>

#define SR      44100.0
#define T_LEN   441000
#define B_ROWS  32
#define CHUNK   32
#define NCH     13782           // ceil(441000/32); last chunk = 8 samples
#define WPR     216             // waves per row = ceil(NCH/64)
#define NWAVE   (B_ROWS * WPR)  // 6912
#define NBLK    (NWAVE / 4)     // 1728 blocks of 4 waves
#define NSEG    8
#define SEGCH   1724            // chunks/segment (segs 0..6); seg 7 = 1714 (both even)
#define ROUNDS  10

// ws layout (floats)
#define WS_T    0               // 256*6 segment totals
#define WS_E    2048            // 256*1024*6 per-thread exclusive rel entries
#define WS_F    1576960         // NCH*B_ROWS*6 chunk finals -> entries (in place)

typedef __attribute__((address_space(1))) const void gconst_t;
typedef __attribute__((address_space(3))) void lds_t;
#define GL2LDS(gp, lp) __builtin_amdgcn_global_load_lds((gconst_t*)(gp), (lds_t*)(lp), 16, 0, 0)

// ---------------- shared helpers ----------------

#define COMPUTE_COEFS_TO_LDS(scoef, qs, gains) do { \
    if (threadIdx.x < 3) { \
      int f = threadIdx.x; \
      double cfq = 100.0 * exp(log(30.0) * (double)f / 3.0); \
      double w0 = 2.0 * M_PI * cfq / SR; \
      double alpha = sin(w0) / (2.0 * (double)qs[f]); \
      double Ag = exp((double)gains[f] * (2.302585092994045684 / 40.0)); \
      double a0 = 1.0 + alpha / Ag; \
      scoef[f*5+0] = (float)((1.0 + alpha * Ag) / a0); \
      scoef[f*5+1] = (float)((-2.0 * cos(w0)) / a0); \
      scoef[f*5+2] = (float)((1.0 - alpha * Ag) / a0); \
      scoef[f*5+3] = (float)((-2.0 * cos(w0)) / a0); \
      scoef[f*5+4] = (float)((1.0 - alpha / Ag) / a0); \
    } \
  } while (0)

#define LOAD_COEFS(cf) \
  const float b00=cf[0],b10=cf[1],b20=cf[2],a10=cf[3],a20=cf[4]; \
  const float b01=cf[5],b11=cf[6],b21=cf[7],a11=cf[8],a21=cf[9]; \
  const float b02=cf[10],b12=cf[11],b22=cf[12],a12=cf[13],a22=cf[14];

#define CASCADE_STEP(xx) do { \
    float y1 = fmaf(b00, (xx), s11); \
    s11 = fmaf(-a10, y1, fmaf(b10, (xx), s21)); \
    s21 = fmaf(-a20, y1, b20 * (xx)); \
    float y2 = fmaf(b01, y1, s12); \
    s12 = fmaf(-a11, y2, fmaf(b11, y1, s22)); \
    s22 = fmaf(-a21, y2, b21 * y1); \
    y3 = fmaf(b02, y2, s13); \
    s13 = fmaf(-a12, y3, fmaf(b12, y2, s23)); \
    s23 = fmaf(-a22, y3, b22 * y2); \
  } while (0)

#define MV6(dst, M, v, add) do { \
    _Pragma("unroll") \
    for (int _i = 0; _i < 6; _i++) { \
      float _s = (add)[_i]; \
      _Pragma("unroll") \
      for (int _k = 0; _k < 6; _k++) _s = fmaf((M)[_i*6+_k], (v)[_k], _s); \
      (dst)[_i] = _s; \
    } \
  } while (0)

// ---------------- kA: chunk final states (zero entry) ----------------
// Per-wave slab: 64 chunks x 32 floats, linear. LDS float4-slot s holds global
// float4 g(s) = (s&~7)|((s&7)^((s>>3)&7)) — involution, line-local, bank-balanced.

__global__ __launch_bounds__(256) void kA_states(const float* __restrict__ x,
                                                 const float* __restrict__ qs,
                                                 const float* __restrict__ gains,
                                                 float* __restrict__ ws) {
  __shared__ float lds[4 * 2048];   // 4 waves x 8KB
  __shared__ float scoef[16];
  int wib = threadIdx.x >> 6, lane = threadIdx.x & 63;
  int gw = blockIdx.x * 4 + wib;
  int row = gw / WPR, wci = gw % WPR;
  long rowbase = (long)row * T_LEN;
  int s0 = wci << 11;
  int span4 = (min(2048, T_LEN - s0)) >> 2;          // 512 or 170
  const float4* xp = (const float4*)(x + rowbase + s0);
  float* slab = lds + (wib << 11);
  if (span4 == 512) {
    #pragma unroll
    for (int i = 0; i < 8; i++) {
      int s = (i << 6) + lane;
      int g = (s & ~7) | ((s & 7) ^ ((s >> 3) & 7));
      GL2LDS(xp + g, slab + (i << 8));
    }
  } else {
    #pragma unroll
    for (int i = 0; i < 8; i++) {
      int s = (i << 6) + lane;
      int g = (s & ~7) | ((s & 7) ^ ((s >> 3) & 7));
      if (g < span4) GL2LDS(xp + g, slab + (i << 8));
    }
  }
  COMPUTE_COEFS_TO_LDS(scoef, qs, gains);
  __syncthreads();
  int ci = (wci << 6) + lane;
  if (ci < NCH) {
    LOAD_COEFS(scoef);
    int rem = min(CHUNK, T_LEN - (ci << 5));
    int n4 = rem >> 2;
    const float* rowp = slab + (lane << 5);
    int xr = lane & 7;
    float s11=0,s21=0,s12=0,s22=0,s13=0,s23=0, y3;
    if (n4 == 8) {
      #pragma unroll
      for (int j4 = 0; j4 < 8; j4++) {
        float4 v = *(const float4*)(rowp + ((j4 ^ xr) << 2));
        CASCADE_STEP(v.x); CASCADE_STEP(v.y); CASCADE_STEP(v.z); CASCADE_STEP(v.w);
      }
    } else {
      for (int j4 = 0; j4 < n4; j4++) {
        float4 v = *(const float4*)(rowp + ((j4 ^ xr) << 2));
        CASCADE_STEP(v.x); CASCADE_STEP(v.y); CASCADE_STEP(v.z); CASCADE_STEP(v.w);
      }
    }
    (void)y3;
    float2* F = (float2*)(ws + WS_F + ((long)row * NCH + ci) * 6);
    F[0] = make_float2(s11, s21); F[1] = make_float2(s12, s22); F[2] = make_float2(s13, s23);
  }
}

// ---------------- per-block double-precision matrix setup ----------------

__device__ __forceinline__ void mm6d(const double* X, const double* Y, double* Z, int t) {
  if (t < 36) {
    int i = t / 6, j = t % 6;
    double s = 0.0;
    #pragma unroll
    for (int k = 0; k < 6; k++) s += X[i*6+k] * Y[k*6+j];
    Z[t] = s;
  }
}

// Computes sW = A^32, sV[k] = W^(2*2^k) (k=0..9), and if WANT_G, sG = W^SEGCH.
template<bool WANT_G>
__device__ __forceinline__ void scan_setup(const float* qs, const float* gains, int t,
                                           double* Da, double* Db, double* Dc, double* Dd,
                                           float* sW, float (*sV)[36], float* sG) {
  __shared__ double dco[3][5];
  if (t < 3) {
    int f = t;
    double cfq = 100.0 * exp(log(30.0) * (double)f / 3.0);
    double w0 = 2.0 * M_PI * cfq / SR;
    double alpha = sin(w0) / (2.0 * (double)qs[f]);
    double Ag = exp((double)gains[f] * (2.302585092994045684 / 40.0));
    double a0 = 1.0 + alpha / Ag;
    dco[f][0] = (1.0 + alpha * Ag) / a0;
    dco[f][1] = (-2.0 * cos(w0)) / a0;
    dco[f][2] = (1.0 - alpha * Ag) / a0;
    dco[f][3] = (-2.0 * cos(w0)) / a0;
    dco[f][4] = (1.0 - alpha / Ag) / a0;
  }
  __syncthreads();
  if (t == 0) {
    double u[7] = {0,0,0,0,0,0,1};
    for (int f = 0; f < 3; f++) {
      double b0=dco[f][0], b1=dco[f][1], b2=dco[f][2], a1=dco[f][3], a2=dco[f][4];
      double yv[7], s1p[7], s2p[7];
      for (int i = 0; i < 7; i++) {
        yv[i]  = b0 * u[i] + ((i == 2*f)   ? 1.0 : 0.0);
        s1p[i] = b1 * u[i] + ((i == 2*f+1) ? 1.0 : 0.0) - a1 * yv[i];
        s2p[i] = b2 * u[i] - a2 * yv[i];
      }
      for (int i = 0; i < 6; i++) { Da[(2*f)*6+i] = s1p[i]; Da[(2*f+1)*6+i] = s2p[i]; }
      for (int i = 0; i < 7; i++) u[i] = yv[i];
    }
  }
  if (WANT_G && t < 36) Dc[t] = (t % 7 == 0) ? 1.0 : 0.0;   // identity
  __syncthreads();
  mm6d(Da, Da, Db, t); __syncthreads();   // A^2
  mm6d(Db, Db, Da, t); __syncthreads();   // A^4
  mm6d(Da, Da, Db, t); __syncthreads();   // A^8
  mm6d(Db, Db, Da, t); __syncthreads();   // A^16
  mm6d(Da, Da, Db, t); __syncthreads();   // A^32 = W (Db)
  if (t < 36) sW[t] = (float)Db[t];
  mm6d(Db, Db, Da, t); __syncthreads();   // V0 = W^2 (Da)
  double* cur = Da; double* oth = Db;
  double* Gc = Dc; double* Gd = Dd;
  // SEGCH = 1724 = sum over k in {1,2,3,4,6,8,9} of 2^(k+1)
  #pragma unroll
  for (int k = 0; k < ROUNDS; k++) {
    if (t < 36) sV[k][t] = (float)cur[t];
    if (WANT_G && ((SEGCH >> (k + 1)) & 1)) {
      __syncthreads();
      mm6d(Gc, cur, Gd, t); __syncthreads();
      double* tm = Gc; Gc = Gd; Gd = tm;
    }
    if (k < ROUNDS - 1) {
      __syncthreads();
      mm6d(cur, cur, oth, t); __syncthreads();
      double* tm = cur; cur = oth; oth = tm;
    }
  }
  if (WANT_G && t < 36) sG[t] = (float)Gc[t];
  __syncthreads();
}

// ---------------- kB1: per-segment fold + 1024-wide scan ----------------

__global__ __launch_bounds__(1024) void kB1_scan(const float* __restrict__ qs,
                                                 const float* __restrict__ gains,
                                                 float* __restrict__ ws) {
  int seg = blockIdx.x & 7, row = blockIdx.x >> 3, t = threadIdx.x;
  __shared__ double Da[36], Db[36], Dc[36], Dd[36];
  __shared__ float sW[36], sV[ROUNDS][36];
  __shared__ float bufA[1024][7], bufB[1024][7];
  scan_setup<false>(qs, gains, t, Da, Db, Dc, Dd, sW, sV, nullptr);

  int segstart = seg * SEGCH;
  int nch = min(SEGCH, NCH - segstart);
  int nact = nch >> 1;             // 862 (857 for seg 7)
  const float* F = ws + WS_F + ((long)row * NCH + segstart) * 6;
  float v[6] = {0,0,0,0,0,0};
  if (t < nact) {
    const float4* Fp = (const float4*)(F + 12 * t);   // 48t bytes: 16B-aligned
    float4 l0 = Fp[0], l1 = Fp[1], l2 = Fp[2];
    float f0[6] = {l0.x, l0.y, l0.z, l0.w, l1.x, l1.y};
    float f1[6] = {l1.z, l1.w, l2.x, l2.y, l2.z, l2.w};
    MV6(v, sW, f0, f1);            // fold: chunk 2t final (=f0) through chunk 2t+1
  }
  #pragma unroll
  for (int i = 0; i < 6; i++) bufA[t][i] = v[i];
  __syncthreads();
  float (*src)[7] = bufA, (*dst)[7] = bufB;
  for (int k = 0; k < ROUNDS; k++) {
    int d = 1 << k;
    float nv[6];
    if (t >= d) {
      MV6(nv, sV[k], src[t-d], src[t]);
    } else {
      #pragma unroll
      for (int i = 0; i < 6; i++) nv[i] = src[t][i];
    }
    #pragma unroll
    for (int i = 0; i < 6; i++) dst[t][i] = nv[i];
    __syncthreads();
    float (*tm)[7] = src; src = dst; dst = tm;
  }
  float* Ep = ws + WS_E + ((long)blockIdx.x * 1024 + t) * 6;
  if (t > 0) {
    #pragma unroll
    for (int i = 0; i < 6; i++) Ep[i] = src[t-1][i];
  } else {
    #pragma unroll
    for (int i = 0; i < 6; i++) Ep[i] = 0.0f;
  }
  if (t == nact - 1) {
    float* Tp = ws + WS_T + (long)blockIdx.x * 6;
    #pragma unroll
    for (int i = 0; i < 6; i++) Tp[i] = src[t][i];
  }
}

// ---------------- kB2: inject segment offsets, write entry states ----------------

__global__ __launch_bounds__(1024) void kB2_inject(const float* __restrict__ qs,
                                                   const float* __restrict__ gains,
                                                   float* __restrict__ ws) {
  int seg = blockIdx.x & 7, row = blockIdx.x >> 3, t = threadIdx.x;
  __shared__ double Da[36], Db[36], Dc[36], Dd[36];
  __shared__ float sW[36], sV[ROUNDS][36], sG[36];
  __shared__ float sT[8][6], sO[6];
  scan_setup<true>(qs, gains, t, Da, Db, Dc, Dd, sW, sV, sG);
  if (t < 48) sT[t/6][t%6] = ws[WS_T + ((long)(row*8) + t/6) * 6 + t%6];
  __syncthreads();
  if (t == 0) {
    float o[6] = {0,0,0,0,0,0};
    for (int s2 = 0; s2 < seg; s2++) {
      float no[6];
      MV6(no, sG, o, sT[s2]);
      #pragma unroll
      for (int i = 0; i < 6; i++) o[i] = no[i];
    }
    #pragma unroll
    for (int i = 0; i < 6; i++) sO[i] = o[i];
  }
  __syncthreads();
  int segstart = seg * SEGCH;
  int nch = min(SEGCH, NCH - segstart);
  int nact = nch >> 1;
  if (t < nact) {
    float e[6];
    #pragma unroll
    for (int i = 0; i < 6; i++) e[i] = sO[i];
    // e = W^(2t) * sO via binary decomposition (sV[k] = W^(2*2^k))
    for (int k = 0; k < ROUNDS; k++) {
      if ((t >> k) & 1) {
        float z[6] = {0,0,0,0,0,0}, ne[6];
        MV6(ne, sV[k], e, z);
        #pragma unroll
        for (int i = 0; i < 6; i++) e[i] = ne[i];
      }
    }
    const float* Er = ws + WS_E + ((long)blockIdx.x * 1024 + t) * 6;
    #pragma unroll
    for (int i = 0; i < 6; i++) e[i] += Er[i];
    // entries: chunk 2t gets e; chunk 2t+1 gets W*e + F(2t)_final
    float4* Fp = (float4*)(ws + WS_F + ((long)row * NCH + segstart) * 6 + 12 * t);
    float4 l0 = Fp[0], l1 = Fp[1], l2 = Fp[2];
    float f0[6] = {l0.x, l0.y, l0.z, l0.w, l1.x, l1.y};
    float e1[6];
    MV6(e1, sW, e, f0);
    (void)l2;
    Fp[0] = make_float4(e[0], e[1], e[2], e[3]);
    Fp[1] = make_float4(e[4], e[5], e1[0], e1[1]);
    Fp[2] = make_float4(e1[2], e1[3], e1[4], e1[5]);
  }
}

// ---------------- kC: exact emit from entry states ----------------

__global__ __launch_bounds__(256) void kC_emit(const float* __restrict__ x,
                                               const float* __restrict__ qs,
                                               const float* __restrict__ gains,
                                               float* __restrict__ y,
                                               const float* __restrict__ ws) {
  __shared__ float lds[4 * 2048];
  __shared__ float scoef[16];
  int wib = threadIdx.x >> 6, lane = threadIdx.x & 63;
  int gw = blockIdx.x * 4 + wib;
  int row = gw / WPR, wci = gw % WPR;
  long rowbase = (long)row * T_LEN;
  int s0 = wci << 11;
  int span4 = (min(2048, T_LEN - s0)) >> 2;
  const float4* xp = (const float4*)(x + rowbase + s0);
  float* slab = lds + (wib << 11);
  if (span4 == 512) {
    #pragma unroll
    for (int i = 0; i < 8; i++) {
      int s = (i << 6) + lane;
      int g = (s & ~7) | ((s & 7) ^ ((s >> 3) & 7));
      GL2LDS(xp + g, slab + (i << 8));
    }
  } else {
    #pragma unroll
    for (int i = 0; i < 8; i++) {
      int s = (i << 6) + lane;
      int g = (s & ~7) | ((s & 7) ^ ((s >> 3) & 7));
      if (g < span4) GL2LDS(xp + g, slab + (i << 8));
    }
  }
  COMPUTE_COEFS_TO_LDS(scoef, qs, gains);
  int ci = (wci << 6) + lane;
  float e0=0,e1=0,e2=0,e3=0,e4=0,e5=0;
  if (ci < NCH) {
    const float2* E = (const float2*)(ws + WS_F + ((long)row * NCH + ci) * 6);
    float2 a = E[0], b = E[1], c = E[2];
    e0=a.x; e1=a.y; e2=b.x; e3=b.y; e4=c.x; e5=c.y;
  }
  __syncthreads();
  if (ci < NCH) {
    LOAD_COEFS(scoef);
    float s11=e0, s21=e1, s12=e2, s22=e3, s13=e4, s23=e5;
    int rem = min(CHUNK, T_LEN - (ci << 5));
    int n4 = rem >> 2;
    float* rowp = slab + (lane << 5);
    int xr = lane & 7;
    float y3;
    if (n4 == 8) {
      #pragma unroll
      for (int j4 = 0; j4 < 8; j4++) {
        float* p = rowp + ((j4 ^ xr) << 2);
        float4 v = *(const float4*)p;
        float4 o;
        CASCADE_STEP(v.x); o.x = y3;
        CASCADE_STEP(v.y); o.y = y3;
        CASCADE_STEP(v.z); o.z = y3;
        CASCADE_STEP(v.w); o.w = y3;
        *(float4*)p = o;
      }
    } else {
      for (int j4 = 0; j4 < n4; j4++) {
        float* p = rowp + ((j4 ^ xr) << 2);
        float4 v = *(const float4*)p;
        float4 o;
        CASCADE_STEP(v.x); o.x = y3;
        CASCADE_STEP(v.y); o.y = y3;
        CASCADE_STEP(v.z); o.z = y3;
        CASCADE_STEP(v.w); o.w = y3;
        *(float4*)p = o;
      }
    }
  }
  __syncthreads();
  float4* yp = (float4*)(y + rowbase + s0);
  if (span4 == 512) {
    #pragma unroll
    for (int i = 0; i < 8; i++) {
      int g = (i << 6) + lane;
      int s = (g & ~7) | ((g & 7) ^ ((g >> 3) & 7));
      yp[g] = *(const float4*)(slab + (s << 2));
    }
  } else {
    #pragma unroll
    for (int i = 0; i < 8; i++) {
      int g = (i << 6) + lane;
      int s = (g & ~7) | ((g & 7) ^ ((g >> 3) & 7));
      if (g < span4) yp[g] = *(const float4*)(slab + (s << 2));
    }
  }
}

extern "C" void kernel_launch(void* const* d_in, const int* in_sizes, int n_in,
                              void* d_out, int out_size, void* d_ws, size_t ws_size,
                              hipStream_t stream) {
  const float* audio = (const float*)d_in[0];
  const float* qs    = (const float*)d_in[1];
  const float* gains = (const float*)d_in[2];
  float* out = (float*)d_out;
  float* ws  = (float*)d_ws;

  hipLaunchKernelGGL(kA_states, dim3(NBLK), dim3(256), 0, stream, audio, qs, gains, ws);
  hipLaunchKernelGGL(kB1_scan, dim3(B_ROWS * NSEG), dim3(1024), 0, stream, qs, gains, ws);
  hipLaunchKernelGGL(kB2_inject, dim3(B_ROWS * NSEG), dim3(1024), 0, stream, qs, gains, ws);
  hipLaunchKernelGGL(kC_emit, dim3(NBLK), dim3(256), 0, stream, audio, qs, gains, out, ws);
}